// Round 4
// baseline (43015.472 us; speedup 1.0000x reference)
//
#include <hip/hip_runtime.h>
#include <math.h>

// Problem constants (from reference)
#define B_ 32
#define N_ 16384
#define K_ 21
#define C_ 64
#define M_ (N_ - K_ + 1)   // 16364
#define T_ 30
// L = 10.0, LAM = 0.1  ->  1/L = 0.1, LAM/L = 0.01

#define TILE 236   // x outputs per block; res width = TILE+20 = 256 = 64*4
#define NT   256   // 4 waves; wave wv owns channels [16wv, 16wv+16)

// One block: batch b, x tile [m0, m0+TILE), all 64 channels.
// Lane l: res positions m0+4l..+3; x_tmp window [g0, g0+24), g0 = m0-20+4l.
// x_tmp built on the fly from Xc/Xo via overlapping global float4 loads
// (L1 absorbs the 6x stencil overlap). xt[16][4] kept in registers across
// phases (constant-indexed, never address-taken -> no scratch).
__global__ __launch_bounds__(NT, 3) void fused_step_kernel(
    const float* __restrict__ Xc, const float* __restrict__ Xo,
    float* __restrict__ Xw, const float* __restrict__ y,
    const float* __restrict__ Hg, const float bp, const float bm,
    const int first)
{
  __shared__ float rp[4][256];   // per-wave convT partials
  __shared__ float rs[256];      // final residual row

  const int tid = threadIdx.x;
  const int wv  = tid >> 6;
  const int l   = tid & 63;
  const int b   = blockIdx.y;
  const int m0  = blockIdx.x * TILE;
  const int g0  = m0 - 20 + 4 * l;

  float xt[16][4];               // x_tmp at this lane's own 4 positions

  if (!first) {
    const bool fast = (g0 >= 0) && (g0 + 23 < M_);
    float p0 = 0.f, p1 = 0.f, p2 = 0.f, p3 = 0.f;

    #pragma unroll
    for (int cl = 0; cl < 16; ++cl) {
      const int cs = __builtin_amdgcn_readfirstlane((wv << 4) + cl);
      const size_t row = ((size_t)b * C_ + cs) * M_;
      const float* pc = Xc + row + g0;
      const float* po = Xo + row + g0;

      float w[24];   // x_tmp window (constant-indexed only)
      if (fast) {
        #pragma unroll
        for (int k = 0; k < 6; ++k) {
          const float4 a = *(const float4*)(pc + 4 * k);
          const float4 o = *(const float4*)(po + 4 * k);
          w[4*k+0] = fmaf(bm, o.x, bp * a.x);   // (1+beta)*xc - beta*xo
          w[4*k+1] = fmaf(bm, o.y, bp * a.y);
          w[4*k+2] = fmaf(bm, o.z, bp * a.z);
          w[4*k+3] = fmaf(bm, o.w, bp * a.w);
        }
      } else {
        #pragma unroll
        for (int e = 0; e < 24; ++e) {
          const int g = g0 + e;
          float a = 0.f, o = 0.f;
          if ((unsigned)g < (unsigned)M_) { a = pc[e]; o = po[e]; }
          w[e] = fmaf(bm, o, bp * a);
        }
      }

      const float* hc = Hg + cs * K_;   // uniform -> s_loads
      #pragma unroll
      for (int u = 0; u < 21; ++u) {
        const float hv = hc[20 - u];
        p0 = fmaf(w[u],     hv, p0);
        p1 = fmaf(w[u + 1], hv, p1);
        p2 = fmaf(w[u + 2], hv, p2);
        p3 = fmaf(w[u + 3], hv, p3);
      }
      xt[cl][0] = w[20]; xt[cl][1] = w[21];
      xt[cl][2] = w[22]; xt[cl][3] = w[23];
    }
    rp[wv][4*l+0] = p0; rp[wv][4*l+1] = p1;
    rp[wv][4*l+2] = p2; rp[wv][4*l+3] = p3;
  } else {
    #pragma unroll
    for (int cl = 0; cl < 16; ++cl) {
      xt[cl][0] = 0.f; xt[cl][1] = 0.f; xt[cl][2] = 0.f; xt[cl][3] = 0.f;
    }
  }
  __syncthreads();

  // finalize residual: rs[i] = y[m0+i] - sum_waves rp   (0 beyond N)
  {
    float r = 0.f;
    const int n = m0 + tid;
    if (n < N_) {
      r = y[(size_t)b * N_ + n];
      if (!first) r -= rp[0][tid] + rp[1][tid] + rp[2][tid] + rp[3][tid];
    }
    rs[tid] = r;
  }
  __syncthreads();

  // gradient step + shrink: x_{t+1}[m0+4l .. +3] per channel
  const int rem = M_ - m0;
  if (l < 59 && 4 * l < rem) {
    float wr[24];
    #pragma unroll
    for (int k = 0; k < 6; ++k) {
      const float4 q = *(const float4*)&rs[4 * l + 4 * k];
      wr[4*k+0] = q.x; wr[4*k+1] = q.y; wr[4*k+2] = q.z; wr[4*k+3] = q.w;
    }
    #pragma unroll
    for (int cl = 0; cl < 16; ++cl) {
      const int cs = __builtin_amdgcn_readfirstlane((wv << 4) + cl);
      const float* hc = Hg + cs * K_;
      float a0 = 0.f, a1 = 0.f, a2 = 0.f, a3 = 0.f;
      #pragma unroll
      for (int u = 0; u < 21; ++u) {
        const float hv = hc[u];
        a0 = fmaf(wr[u],     hv, a0);
        a1 = fmaf(wr[u + 1], hv, a1);
        a2 = fmaf(wr[u + 2], hv, a2);
        a3 = fmaf(wr[u + 3], hv, a3);
      }
      float o0 = fmaf(a0, 0.1f, xt[cl][0]) - 0.01f;
      float o1 = fmaf(a1, 0.1f, xt[cl][1]) - 0.01f;
      float o2 = fmaf(a2, 0.1f, xt[cl][2]) - 0.01f;
      float o3 = fmaf(a3, 0.1f, xt[cl][3]) - 0.01f;
      o0 = fmaxf(o0, 0.f); o1 = fmaxf(o1, 0.f);
      o2 = fmaxf(o2, 0.f); o3 = fmaxf(o3, 0.f);
      const size_t row = ((size_t)b * C_ + cs) * M_;
      *(float4*)(Xw + row + m0 + 4 * l) = make_float4(o0, o1, o2, o3);
    }
  }
}

// y_hat[n] = sum_c sum_j x[c][n-j] * H[c][j], 256 outputs per block
__global__ __launch_bounds__(NT, 3) void yhat_kernel(
    const float* __restrict__ X, const float* __restrict__ Hg,
    float* __restrict__ out)
{
  __shared__ float rp[4][256];
  const int tid = threadIdx.x;
  const int wv  = tid >> 6;
  const int l   = tid & 63;
  const int b   = blockIdx.y;
  const int r0  = blockIdx.x * 256;
  const int g0  = r0 - 20 + 4 * l;
  const bool fast = (g0 >= 0) && (g0 + 23 < M_);

  float p0 = 0.f, p1 = 0.f, p2 = 0.f, p3 = 0.f;
  #pragma unroll
  for (int cl = 0; cl < 16; ++cl) {
    const int cs = __builtin_amdgcn_readfirstlane((wv << 4) + cl);
    const float* pc = X + ((size_t)b * C_ + cs) * M_ + g0;
    float w[24];
    if (fast) {
      #pragma unroll
      for (int k = 0; k < 6; ++k) {
        const float4 a = *(const float4*)(pc + 4 * k);
        w[4*k+0] = a.x; w[4*k+1] = a.y; w[4*k+2] = a.z; w[4*k+3] = a.w;
      }
    } else {
      #pragma unroll
      for (int e = 0; e < 24; ++e) {
        const int g = g0 + e;
        w[e] = ((unsigned)g < (unsigned)M_) ? pc[e] : 0.f;
      }
    }
    const float* hc = Hg + cs * K_;
    #pragma unroll
    for (int u = 0; u < 21; ++u) {
      const float hv = hc[20 - u];
      p0 = fmaf(w[u],     hv, p0);
      p1 = fmaf(w[u + 1], hv, p1);
      p2 = fmaf(w[u + 2], hv, p2);
      p3 = fmaf(w[u + 3], hv, p3);
    }
  }
  rp[wv][4*l+0] = p0; rp[wv][4*l+1] = p1;
  rp[wv][4*l+2] = p2; rp[wv][4*l+3] = p3;
  __syncthreads();

  out[(size_t)b * N_ + r0 + tid] =
      rp[0][tid] + rp[1][tid] + rp[2][tid] + rp[3][tid];
}

extern "C" void kernel_launch(void* const* d_in, const int* in_sizes, int n_in,
                              void* d_out, int out_size, void* d_ws, size_t ws_size,
                              hipStream_t stream)
{
  const float* y = (const float*)d_in[0];   // [B,1,N] fp32
  const float* H = (const float*)d_in[1];   // [C,1,K] fp32
  float* out  = (float*)d_out;
  float* outy = out;                         // [B,N] y_hat region
  float* outx = out + (size_t)B_ * N_;       // [B,C,M] x region

  const size_t SZ = (size_t)B_ * C_ * M_;    // floats per x buffer

  // FISTA momentum: betas[t] = (s_t - 1)/s_{t+1}, s_0 = 1 (betas[0] = 0)
  float betas[T_];
  double s = 1.0;
  for (int t = 0; t < T_; ++t) {
    const double sn = (1.0 + sqrt(1.0 + 4.0 * s * s)) * 0.5;
    betas[t] = (float)((s - 1.0) / sn);
    s = sn;
  }

  // 3 rotating x buffers; rotation lands x_30 in outx at t=29.
  float* P[3] = { (float*)d_ws, (float*)d_ws + SZ, outx };
  const dim3 blk(NT);
  const dim3 gF((M_ + TILE - 1) / TILE, B_);   // 70 x 32
  for (int t = 0; t < T_; ++t) {
    const float beta = (t >= 1) ? betas[t - 1] : 0.f;
    const float* Xc = P[(t + 2) % 3];          // x_t     (unused when t==0)
    const float* Xo = (beta != 0.f) ? P[(t + 1) % 3] : Xc;   // x_{t-1}
    float*       Xw = P[t % 3];                // x_{t+1}
    fused_step_kernel<<<gF, blk, 0, stream>>>(Xc, Xo, Xw, y, H,
                                              1.f + beta, -beta, t == 0);
  }
  const dim3 gY(N_ / 256, B_);                 // 64 x 32
  yhat_kernel<<<gY, blk, 0, stream>>>(outx, H, outy);
}

// Round 5
// 3886.786 us; speedup vs baseline: 11.0671x; 11.0671x over previous
//
#include <hip/hip_runtime.h>
#include <math.h>

// Problem constants (from reference)
#define B_ 32
#define N_ 16384
#define K_ 21
#define C_ 64
#define M_ (N_ - K_ + 1)   // 16364
#define T_ 30
// L = 10.0, LAM = 0.1  ->  1/L = 0.1, LAM/L = 0.01

#define TILE 236   // x outputs per block; res width = 256
#define XWID 276   // staged x_tmp width = TILE + 40
#define Q4PC 69    // float4 per staged row (XWID/4)
#define NQ4  (16 * Q4PC)   // 1104 float4 per 16-channel chunk
#define NT   256   // 4 waves

// One block: batch b, x tile [m0, m0+TILE), all 64 channels in 4 chunks.
// Chunk k: stage x_tmp(16 ch) into LDS; wave wv accumulates convT partials
// for channels wv*4..wv*4+3 into 4 registers (p0..p3, its lane's 4 res
// positions). After 4 chunks: reduce across waves -> rs (residual).
// Phase 3: conv(rs) + shrink; x_tmp at own positions re-read from global
// (coalesced, L2-hot). NO private array crosses the channel loop -> no scratch.
__global__ __launch_bounds__(NT, 4) void fused_step_kernel(
    const float* __restrict__ Xc, const float* __restrict__ Xo,
    float* __restrict__ Xw, const float* __restrict__ y,
    const float* __restrict__ Hg, const float bp, const float bm,
    const int first)
{
  __shared__ float xs[16][XWID];   // 17664 B  staged x_tmp chunk
  __shared__ float rp[4][256];     //  4096 B  per-wave convT partials
  __shared__ float rs[256];        //  1024 B  final residual row

  const int tid = threadIdx.x;
  const int wv  = tid >> 6;
  const int l   = tid & 63;
  const int b   = blockIdx.y;
  const int m0  = blockIdx.x * TILE;
  const int g0  = m0 - 20;
  const bool has_o = (bm != 0.f);

  if (!first) {
    float p0 = 0.f, p1 = 0.f, p2 = 0.f, p3 = 0.f;

    for (int k = 0; k < 4; ++k) {
      const int ch0 = k << 4;
      const float* pcb = Xc + ((size_t)b * C_ + ch0) * M_;
      const float* pob = Xo + ((size_t)b * C_ + ch0) * M_;

      __syncthreads();   // previous chunk's LDS reads complete
      // ---- stage chunk: x_tmp = bp*Xc + bm*Xo, zero-padded ----
      for (int f = tid; f < NQ4; f += NT) {
        const int c  = f / Q4PC;
        const int i4 = f - c * Q4PC;
        const int g  = g0 + (i4 << 2);
        const float* pa = pcb + (size_t)c * M_ + g;
        const float* pb = pob + (size_t)c * M_ + g;
        float ax, ay, az, aw, ox, oy, oz, ow;
        if (g >= 0 && g + 3 < M_) {
          const float4 a = *(const float4*)pa;
          ax = a.x; ay = a.y; az = a.z; aw = a.w;
          if (has_o) {
            const float4 o = *(const float4*)pb;
            ox = o.x; oy = o.y; oz = o.z; ow = o.w;
          } else { ox = oy = oz = ow = 0.f; }
        } else {
          ax = ay = az = aw = ox = oy = oz = ow = 0.f;
          if ((unsigned)(g+0) < (unsigned)M_) { ax = pa[0]; if (has_o) ox = pb[0]; }
          if ((unsigned)(g+1) < (unsigned)M_) { ay = pa[1]; if (has_o) oy = pb[1]; }
          if ((unsigned)(g+2) < (unsigned)M_) { az = pa[2]; if (has_o) oz = pb[2]; }
          if ((unsigned)(g+3) < (unsigned)M_) { aw = pa[3]; if (has_o) ow = pb[3]; }
        }
        float4 w4;
        w4.x = fmaf(bm, ox, bp * ax);
        w4.y = fmaf(bm, oy, bp * ay);
        w4.z = fmaf(bm, oz, bp * az);
        w4.w = fmaf(bm, ow, bp * aw);
        *(float4*)&xs[c][i4 << 2] = w4;
      }
      __syncthreads();

      // ---- convT partials: wave wv handles 4 channels of this chunk ----
      #pragma unroll
      for (int j = 0; j < 4; ++j) {
        const int cloc = (wv << 2) + j;
        const int cg = __builtin_amdgcn_readfirstlane(ch0 + cloc);
        const float* hc = Hg + cg * K_;   // uniform -> s_loads
        float w[24];
        #pragma unroll
        for (int kk = 0; kk < 6; ++kk) {
          const float4 v = *(const float4*)&xs[cloc][(l << 2) + (kk << 2)];
          w[4*kk+0] = v.x; w[4*kk+1] = v.y;
          w[4*kk+2] = v.z; w[4*kk+3] = v.w;
        }
        #pragma unroll
        for (int u = 0; u < 21; ++u) {
          const float hv = hc[20 - u];
          p0 = fmaf(w[u],     hv, p0);
          p1 = fmaf(w[u + 1], hv, p1);
          p2 = fmaf(w[u + 2], hv, p2);
          p3 = fmaf(w[u + 3], hv, p3);
        }
      }
    }
    *(float4*)&rp[wv][l << 2] = make_float4(p0, p1, p2, p3);
  }
  __syncthreads();

  // ---- finalize residual ----
  {
    const int n = m0 + tid;
    float r = 0.f;
    if (n < N_) {
      r = y[(size_t)b * N_ + n];
      if (!first) r -= rp[0][tid] + rp[1][tid] + rp[2][tid] + rp[3][tid];
    }
    rs[tid] = r;
  }
  __syncthreads();

  // ---- gradient step + shrink: wave wv writes channels [16wv,16wv+16) ----
  if (l < 59 && (l << 2) < M_ - m0) {
    float wr[24];
    #pragma unroll
    for (int kk = 0; kk < 6; ++kk) {
      const float4 v = *(const float4*)&rs[(l << 2) + (kk << 2)];
      wr[4*kk+0] = v.x; wr[4*kk+1] = v.y;
      wr[4*kk+2] = v.z; wr[4*kk+3] = v.w;
    }
    #pragma unroll 4
    for (int cl = 0; cl < 16; ++cl) {
      const int cg = __builtin_amdgcn_readfirstlane((wv << 4) + cl);
      const size_t row = ((size_t)b * C_ + cg) * M_ + m0 + (l << 2);
      float xt0, xt1, xt2, xt3;
      if (!first) {
        const float4 a = *(const float4*)(Xc + row);
        float ox = 0.f, oy = 0.f, oz = 0.f, ow = 0.f;
        if (has_o) {
          const float4 o = *(const float4*)(Xo + row);
          ox = o.x; oy = o.y; oz = o.z; ow = o.w;
        }
        xt0 = fmaf(bm, ox, bp * a.x);
        xt1 = fmaf(bm, oy, bp * a.y);
        xt2 = fmaf(bm, oz, bp * a.z);
        xt3 = fmaf(bm, ow, bp * a.w);
      } else { xt0 = xt1 = xt2 = xt3 = 0.f; }

      const float* hc = Hg + cg * K_;
      float a0 = 0.f, a1 = 0.f, a2 = 0.f, a3 = 0.f;
      #pragma unroll
      for (int u = 0; u < 21; ++u) {
        const float hv = hc[u];
        a0 = fmaf(wr[u],     hv, a0);
        a1 = fmaf(wr[u + 1], hv, a1);
        a2 = fmaf(wr[u + 2], hv, a2);
        a3 = fmaf(wr[u + 3], hv, a3);
      }
      const float o0 = fmaxf(fmaf(a0, 0.1f, xt0) - 0.01f, 0.f);
      const float o1 = fmaxf(fmaf(a1, 0.1f, xt1) - 0.01f, 0.f);
      const float o2 = fmaxf(fmaf(a2, 0.1f, xt2) - 0.01f, 0.f);
      const float o3 = fmaxf(fmaf(a3, 0.1f, xt3) - 0.01f, 0.f);
      *(float4*)(Xw + row) = make_float4(o0, o1, o2, o3);
    }
  }
}

// ---------------- convT kernel for final y_hat (round-1, proven) ----------
#define TA 1024
#define CC 16
#define NTHR 256

__global__ __launch_bounds__(NTHR) void convT_kernel(
    const float* __restrict__ X, const float* __restrict__ y,
    const float* __restrict__ Hg, float* __restrict__ out,
    const int use_y, const float sign)
{
  __shared__ float xs[CC][TA + 20];
  __shared__ float hs[C_][K_];
  const int tid = threadIdx.x;
  const int b = blockIdx.y;
  const int n0 = blockIdx.x * TA;

  for (int f = tid; f < C_ * K_; f += NTHR) hs[f / K_][f % K_] = sign * Hg[f];

  float acc[4];
  if (use_y) {
    const float4 v = *(const float4*)(y + (size_t)b * N_ + n0 + tid * 4);
    acc[0] = v.x; acc[1] = v.y; acc[2] = v.z; acc[3] = v.w;
  } else {
    acc[0] = acc[1] = acc[2] = acc[3] = 0.f;
  }

  const bool interior = (n0 >= 20) && (n0 + TA - 1 <= M_ - 1);
  const int QROW = (TA + 20) / 4;

  for (int cb = 0; cb < C_; cb += CC) {
    __syncthreads();
    for (int f = tid; f < CC * QROW; f += NTHR) {
      const int c = f / QROW;
      const int i = (f % QROW) * 4;
      const int gx = n0 - 20 + i;
      const float* src = X + ((size_t)(b * C_ + cb + c)) * M_ + gx;
      float4 v;
      if (interior) {
        v = *(const float4*)src;
      } else {
        v.x = (gx >= 0     && gx < M_)     ? src[0] : 0.f;
        v.y = (gx + 1 >= 0 && gx + 1 < M_) ? src[1] : 0.f;
        v.z = (gx + 2 >= 0 && gx + 2 < M_) ? src[2] : 0.f;
        v.w = (gx + 3 >= 0 && gx + 3 < M_) ? src[3] : 0.f;
      }
      *(float4*)&xs[c][i] = v;
    }
    __syncthreads();

    for (int c = 0; c < CC; ++c) {
      float w[24];
      #pragma unroll
      for (int k = 0; k < 6; ++k) {
        const float4 v = *(const float4*)&xs[c][tid * 4 + k * 4];
        w[k*4] = v.x; w[k*4+1] = v.y; w[k*4+2] = v.z; w[k*4+3] = v.w;
      }
      const float* hr = hs[cb + c];
      #pragma unroll
      for (int j = 0; j < K_; ++j) {
        const float h = hr[j];
        acc[0] = fmaf(h, w[20 - j], acc[0]);
        acc[1] = fmaf(h, w[21 - j], acc[1]);
        acc[2] = fmaf(h, w[22 - j], acc[2]);
        acc[3] = fmaf(h, w[23 - j], acc[3]);
      }
    }
  }

  *(float4*)(out + (size_t)b * N_ + n0 + tid * 4) =
      make_float4(acc[0], acc[1], acc[2], acc[3]);
}

extern "C" void kernel_launch(void* const* d_in, const int* in_sizes, int n_in,
                              void* d_out, int out_size, void* d_ws, size_t ws_size,
                              hipStream_t stream)
{
  const float* y = (const float*)d_in[0];   // [B,1,N] fp32
  const float* H = (const float*)d_in[1];   // [C,1,K] fp32
  float* out  = (float*)d_out;
  float* outy = out;                         // [B,N] y_hat region
  float* outx = out + (size_t)B_ * N_;       // [B,C,M] x region

  const size_t SZ = (size_t)B_ * C_ * M_;    // floats per x buffer

  // FISTA momentum: betas[t] = (s_t - 1)/s_{t+1}, s_0 = 1 (betas[0] = 0)
  float betas[T_];
  double s = 1.0;
  for (int t = 0; t < T_; ++t) {
    const double sn = (1.0 + sqrt(1.0 + 4.0 * s * s)) * 0.5;
    betas[t] = (float)((s - 1.0) / sn);
    s = sn;
  }

  // 3 rotating x buffers; rotation lands x_30 in outx at t=29.
  float* P[3] = { (float*)d_ws, (float*)d_ws + SZ, outx };
  const dim3 blk(NT);
  const dim3 gF((M_ + TILE - 1) / TILE, B_);   // 70 x 32
  for (int t = 0; t < T_; ++t) {
    const float beta = (t >= 1) ? betas[t - 1] : 0.f;
    const float* Xc = P[(t + 2) % 3];          // x_t     (unused when t==0)
    const float* Xo = (beta != 0.f) ? P[(t + 1) % 3] : Xc;   // x_{t-1}
    float*       Xw = P[t % 3];                // x_{t+1}
    fused_step_kernel<<<gF, blk, 0, stream>>>(Xc, Xo, Xw, y, H,
                                              1.f + beta, -beta, t == 0);
  }
  const dim3 gA(N_ / TA, B_);
  convT_kernel<<<gA, dim3(NTHR), 0, stream>>>(outx, y, H, outy, 0, 1.f);
}